// Round 5
// baseline (269.286 us; speedup 1.0000x reference)
//
#include <hip/hip_runtime.h>
#include <hip/hip_bf16.h>

#define P_CLS 512
#define D_DIM 2048
#define CAP   32
#define TAU_INV 2.0f

typedef short short8 __attribute__((ext_vector_type(8)));
typedef float f32x4 __attribute__((ext_vector_type(4)));

__device__ __forceinline__ unsigned short f2bf_bits(float x) {
  __hip_bfloat16 b = __float2bfloat16(x);
  unsigned short u;
  __builtin_memcpy(&u, &b, sizeof(u));
  return u;
}

__device__ __forceinline__ float xred_sum(float v) {
#pragma unroll
  for (int o = 1; o < 64; o <<= 1) v += __shfl_xor(v, o, 64);
  return v;
}
__device__ __forceinline__ float xred_max(float v) {
#pragma unroll
  for (int o = 1; o < 64; o <<= 1) v = fmaxf(v, __shfl_xor(v, o, 64));
  return v;
}

// init (cnt, accs) + label->index build, one block, LDS atomics.
__global__ __launch_bounds__(1024)
void k_prep(const int* __restrict__ label, int* __restrict__ cnt,
            int* __restrict__ idx, float* __restrict__ accs, int n) {
  __shared__ int lcnt[P_CLS];
  int t = threadIdx.x;
  if (t < P_CLS) lcnt[t] = 0;
  if (t >= P_CLS && t < P_CLS + 8) accs[t - P_CLS] = 0.f;
  __syncthreads();
  for (int i = t; i < n; i += 1024) {
    int p = label[i];
    int slot = atomicAdd(&lcnt[p], 1);
    if (slot < CAP) idx[p * CAP + slot] = i;
  }
  __syncthreads();
  if (t < P_CLS) cnt[t] = lcnt[t];
}

// Block per (class p, modality m); wave wv owns cols [wv*512, wv*512+512).
// Per lane: 8 floats (two f32x4). Depth-2 register prefetch over the c rows;
// ONE barrier per row (parity-buffered scratch). ~0 LDS -> all blocks resident.
__global__ __launch_bounds__(256)
void k_centers(const float* __restrict__ f0, const float* __restrict__ f1,
               const float* __restrict__ f2, const int* __restrict__ cnt,
               const int* __restrict__ idx, __hip_bfloat16* __restrict__ cb,
               float* __restrict__ accs) {
  __shared__ float scr[2][4];
  __shared__ float s2s[4];
  int p = blockIdx.x, m = blockIdx.y;
  const float* F = (m == 0) ? f0 : (m == 1) ? f1 : f2;
  int t = threadIdx.x, lane = t & 63, wv = t >> 6;
  int c = cnt[p];
  if (c > CAP) c = CAP;
  const int* idxp = idx + p * CAP;
  int col0 = wv * 512 + lane * 4;
  f32x4 acc0 = {0, 0, 0, 0}, acc1 = {0, 0, 0, 0};
  if (c > 0) {
    const float* rp0 = F + (long)idxp[0] * D_DIM;
    f32x4 v0 = *(const f32x4*)(rp0 + col0);
    f32x4 v1 = *(const f32x4*)(rp0 + col0 + 256);
    f32x4 n10 = {0,0,0,0}, n11 = {0,0,0,0};
    if (c > 1) {
      const float* rp1 = F + (long)idxp[1] * D_DIM;
      n10 = *(const f32x4*)(rp1 + col0);
      n11 = *(const f32x4*)(rp1 + col0 + 256);
    }
    for (int r = 0; r < c; ++r) {
      f32x4 n20 = {0,0,0,0}, n21 = {0,0,0,0};
      if (r + 2 < c) {
        const float* rp2 = F + (long)idxp[r + 2] * D_DIM;
        n20 = *(const f32x4*)(rp2 + col0);
        n21 = *(const f32x4*)(rp2 + col0 + 256);
      }
      f32x4 q = v0 * v0 + v1 * v1;
      float ssq = q.x + q.y + q.z + q.w;
      ssq = xred_sum(ssq);
      if (lane == 0) scr[r & 1][wv] = ssq;
      __syncthreads();
      float tot = scr[r & 1][0] + scr[r & 1][1] + scr[r & 1][2] + scr[r & 1][3];
      float w = 1.0f / fmaxf(sqrtf(tot), 1e-12f);
      acc0 += v0 * w;
      acc1 += v1 * w;
      v0 = n10; v1 = n11;
      n10 = n20; n11 = n21;
    }
  }
  f32x4 q = acc0 * acc0 + acc1 * acc1;
  float s2 = q.x + q.y + q.z + q.w;
  s2 = xred_sum(s2);
  if (lane == 0) s2s[wv] = s2;
  __syncthreads();
  float sn = sqrtf(s2s[0] + s2s[1] + s2s[2] + s2s[3]);
  float inv = 1.0f / fmaxf(sn, 1e-12f);
  __hip_bfloat16* dst = cb + ((long)m * P_CLS + p) * D_DIM;
  f32x4 o0 = acc0 * inv, o1 = acc1 * inv;
  ushort4 h0, h1;
  h0.x = f2bf_bits(o0.x); h0.y = f2bf_bits(o0.y);
  h0.z = f2bf_bits(o0.z); h0.w = f2bf_bits(o0.w);
  h1.x = f2bf_bits(o1.x); h1.y = f2bf_bits(o1.y);
  h1.z = f2bf_bits(o1.z); h1.w = f2bf_bits(o1.w);
  *(ushort4*)(dst + col0) = h0;
  *(ushort4*)(dst + col0 + 256) = h1;
  if (t == 0 && c > 0) atomicAdd(&accs[0], sn);
}

// Split-K bf16 MFMA GEMM (gridDim.z slices), 64x64 tiles, LDS double-buffer
// + depth-2 reg prefetch, one barrier per K-step.
__global__ __launch_bounds__(256)
void k_gemm(const __hip_bfloat16* __restrict__ cbh, float* __restrict__ logits) {
  __shared__ __align__(16) unsigned short As[2][64 * 40], Bs[2][64 * 40];
  int pair = blockIdx.y, kz = blockIdx.z, nkz = gridDim.z;
  int ksl = D_DIM / nkz;
  int ma = (pair == 2) ? 1 : 0;
  int mb = (pair == 0) ? 1 : 2;
  const unsigned short* A =
      (const unsigned short*)cbh + (long)ma * P_CLS * D_DIM + kz * ksl;
  const unsigned short* B =
      (const unsigned short*)cbh + (long)mb * P_CLS * D_DIM + kz * ksl;
  float* C = logits + ((long)kz * 3 + pair) * P_CLS * P_CLS;
  int tm = (blockIdx.x >> 3) * 64, tn = (blockIdx.x & 7) * 64;
  int t = threadIdx.x, lane = t & 63, wv = t >> 6;
  int srow = t >> 2, skc = (t & 3) * 8;
  int quad = lane >> 4, mr = lane & 15;
  const unsigned short* pa = A + (long)(tm + srow) * D_DIM + skc;
  const unsigned short* pb = B + (long)(tn + srow) * D_DIM + skc;
  f32x4 acc[4] = {{0,0,0,0},{0,0,0,0},{0,0,0,0},{0,0,0,0}};
  uint4 av = *(const uint4*)pa, bv = *(const uint4*)pb;
  *(uint4*)(&As[0][srow * 40 + skc]) = av;
  *(uint4*)(&Bs[0][srow * 40 + skc]) = bv;
  av = *(const uint4*)(pa + 32); bv = *(const uint4*)(pb + 32);
  const int NIT = ksl / 32;
  for (int it = 0; it < NIT; ++it) {
    __syncthreads();
    int cur = it & 1;
    if (it + 1 < NIT) {
      *(uint4*)(&As[cur ^ 1][srow * 40 + skc]) = av;
      *(uint4*)(&Bs[cur ^ 1][srow * 40 + skc]) = bv;
    }
    if (it + 2 < NIT) {
      av = *(const uint4*)(pa + (it + 2) * 32);
      bv = *(const uint4*)(pb + (it + 2) * 32);
    }
    short8 af = *(const short8*)(&As[cur][(wv * 16 + mr) * 40 + quad * 8]);
#pragma unroll
    for (int nb = 0; nb < 4; ++nb) {
      short8 bfr = *(const short8*)(&Bs[cur][(nb * 16 + mr) * 40 + quad * 8]);
      acc[nb] = __builtin_amdgcn_mfma_f32_16x16x32_bf16(af, bfr, acc[nb], 0, 0, 0);
    }
  }
  int crow = tm + wv * 16 + quad * 4;
#pragma unroll
  for (int nb = 0; nb < 4; ++nb)
#pragma unroll
    for (int r = 0; r < 4; ++r)
      C[(long)(crow + r) * P_CLS + tn + nb * 16 + mr] = acc[nb][r] * TAU_INV;
}

// One block per (pair,p) row: sum nkz split-K partials, logsumexp - diag,
// accumulate; LAST block (device-scope counter) composes the final scalar.
__global__ __launch_bounds__(256)
void k_lse(const float* __restrict__ logits, float* __restrict__ accs, int nkz,
           float* __restrict__ out, float invN) {
  __shared__ float sred[8];
  int row = blockIdx.x;  // 0 .. 3*P-1
  int p = row & (P_CLS - 1);
  int t = threadIdx.x, lane = t & 63, wv = t >> 6;
  float v0 = 0.f, v1 = 0.f;
  for (int z = 0; z < nkz; ++z) {
    const float* L = logits + ((long)z * 3 * P_CLS + row) * P_CLS;
    v0 += L[t];
    v1 += L[t + 256];
  }
  float mx = xred_max(fmaxf(v0, v1));
  if (lane == 0) sred[wv] = mx;
  __syncthreads();
  mx = fmaxf(fmaxf(sred[0], sred[1]), fmaxf(sred[2], sred[3]));
  float e = expf(v0 - mx) + expf(v1 - mx);
  e = xred_sum(e);
  if (lane == 0) sred[4 + wv] = e;
  __syncthreads();
  if (t == 0) {
    float tot = sred[4] + sred[5] + sred[6] + sred[7];
    float diag = 0.f;
    for (int z = 0; z < nkz; ++z)
      diag += logits[((long)z * 3 * P_CLS + row) * P_CLS + p];
    atomicAdd(&accs[1], mx + logf(tot) - diag);
    __threadfence();
    int old = atomicAdd((int*)&accs[2], 1);
    if (old == gridDim.x - 1) {
      float li = atomicAdd(&accs[1], 0.f);   // coherent read: all adds done
      float ls = atomicAdd(&accs[0], 0.f);
      out[0] = 6.0f - 2.0f * invN * ls + li * (1.0f / (float)P_CLS);
    }
  }
}

extern "C" void kernel_launch(void* const* d_in, const int* in_sizes, int n_in,
                              void* d_out, int out_size, void* d_ws, size_t ws_size,
                              hipStream_t stream) {
  const float* fvp = (const float*)d_in[0];
  const float* fap = (const float*)d_in[1];
  const float* frp = (const float*)d_in[2];
  const int* label = (const int*)d_in[3];
  int N = in_sizes[3];

  char* ws = (char*)d_ws;
  int* cnt = (int*)ws;                                    // 2 KiB
  int* idx = (int*)(ws + 2048);                           // 64 KiB
  float* accs = (float*)(ws + 2048 + 65536);              // 32 B
  __hip_bfloat16* cb = (__hip_bfloat16*)(ws + 131072);    // 6 MiB
  float* logits = (float*)(ws + 131072 + 3ul * P_CLS * D_DIM * 2);

  size_t base = 131072 + 3ul * P_CLS * D_DIM * 2;
  size_t per_z = 3ul * P_CLS * P_CLS * 4;
  int KZ = (ws_size >= base + 4 * per_z) ? 4 : 2;

  hipLaunchKernelGGL(k_prep, dim3(1), dim3(1024), 0, stream, label, cnt, idx,
                     accs, N);
  hipLaunchKernelGGL(k_centers, dim3(P_CLS, 3), dim3(256), 0, stream,
                     fvp, fap, frp, cnt, idx, cb, accs);
  hipLaunchKernelGGL(k_gemm, dim3(64, 3, KZ), dim3(256), 0, stream, cb, logits);
  hipLaunchKernelGGL(k_lse, dim3(3 * P_CLS), dim3(256), 0, stream, logits, accs,
                     KZ, (float*)d_out, 1.0f / (float)N);
}

// Round 6
// 249.793 us; speedup vs baseline: 1.0780x; 1.0780x over previous
//
#include <hip/hip_runtime.h>
#include <hip/hip_bf16.h>

#define P_CLS 512
#define D_DIM 2048
#define CAP   32
#define TAU_INV 2.0f

typedef short short8 __attribute__((ext_vector_type(8)));
typedef float f32x4 __attribute__((ext_vector_type(4)));

__device__ __forceinline__ unsigned short f2bf_bits(float x) {
  __hip_bfloat16 b = __float2bfloat16(x);
  unsigned short u;
  __builtin_memcpy(&u, &b, sizeof(u));
  return u;
}

__device__ __forceinline__ float xred_sum(float v) {
#pragma unroll
  for (int o = 1; o < 64; o <<= 1) v += __shfl_xor(v, o, 64);
  return v;
}
__device__ __forceinline__ float xred_max(float v) {
#pragma unroll
  for (int o = 1; o < 64; o <<= 1) v = fmaxf(v, __shfl_xor(v, o, 64));
  return v;
}

// init (cnt, accs) + label->index build, one block, LDS atomics.
__global__ __launch_bounds__(1024)
void k_prep(const int* __restrict__ label, int* __restrict__ cnt,
            int* __restrict__ idx, float* __restrict__ accs, int n) {
  __shared__ int lcnt[P_CLS];
  int t = threadIdx.x;
  if (t < P_CLS) lcnt[t] = 0;
  if (t >= P_CLS && t < P_CLS + 8) accs[t - P_CLS] = 0.f;
  __syncthreads();
  for (int i = t; i < n; i += 1024) {
    int p = label[i];
    int slot = atomicAdd(&lcnt[p], 1);
    if (slot < CAP) idx[p * CAP + slot] = i;
  }
  __syncthreads();
  if (t < P_CLS) cnt[t] = lcnt[t];
}

// Block per (class p, modality m); wave wv owns cols [wv*512, wv*512+512).
// Rows processed in groups of 8: all 16 f32x4 loads issued as a batch
// (8 KB/wave in flight), one 8-wide vectorized shuffle-reduction chain and
// ONE barrier per group (parity-buffered scratch). launch_bounds(256,4)
// gives the RA a 128-VGPR budget so the group stays live in registers.
__global__ __launch_bounds__(256, 4)
void k_centers(const float* __restrict__ f0, const float* __restrict__ f1,
               const float* __restrict__ f2, const int* __restrict__ cnt,
               const int* __restrict__ idx, __hip_bfloat16* __restrict__ cb,
               float* __restrict__ accs) {
  __shared__ f32x4 scr[2][4][2];
  __shared__ float s2s[4];
  int p = blockIdx.x, m = blockIdx.y;
  const float* F = (m == 0) ? f0 : (m == 1) ? f1 : f2;
  int t = threadIdx.x, lane = t & 63, wv = t >> 6;
  int c = cnt[p];
  if (c > CAP) c = CAP;
  const int* idxp = idx + p * CAP;
  int col0 = wv * 512 + lane * 4;
  f32x4 acc0 = {0, 0, 0, 0}, acc1 = {0, 0, 0, 0};
  int ng = (c + 7) >> 3;
  for (int g = 0; g < ng; ++g) {
    int rbase = g * 8;
    f32x4 v0[8], v1[8];
#pragma unroll
    for (int j = 0; j < 8; ++j) {
      int rr = rbase + j;
      if (rr >= c) rr = c - 1;
      const float* rp = F + (long)idxp[rr] * D_DIM + col0;
      v0[j] = *(const f32x4*)rp;
      v1[j] = *(const f32x4*)(rp + 256);
    }
    f32x4 sa, sb;
#pragma unroll
    for (int j = 0; j < 4; ++j) {
      f32x4 qa = v0[j] * v0[j] + v1[j] * v1[j];
      sa[j] = qa.x + qa.y + qa.z + qa.w;
      f32x4 qb = v0[j + 4] * v0[j + 4] + v1[j + 4] * v1[j + 4];
      sb[j] = qb.x + qb.y + qb.z + qb.w;
    }
#pragma unroll
    for (int o = 1; o < 64; o <<= 1) {
#pragma unroll
      for (int j = 0; j < 4; ++j) {
        sa[j] += __shfl_xor(sa[j], o, 64);
        sb[j] += __shfl_xor(sb[j], o, 64);
      }
    }
    int par = g & 1;
    if (lane == 0) {
      scr[par][wv][0] = sa;
      scr[par][wv][1] = sb;
    }
    __syncthreads();
    f32x4 ta = scr[par][0][0] + scr[par][1][0] + scr[par][2][0] + scr[par][3][0];
    f32x4 tb = scr[par][0][1] + scr[par][1][1] + scr[par][2][1] + scr[par][3][1];
#pragma unroll
    for (int j = 0; j < 8; ++j) {
      float tot = (j < 4) ? ta[j] : tb[j - 4];
      float w = (rbase + j < c) ? (1.0f / fmaxf(sqrtf(tot), 1e-12f)) : 0.f;
      acc0 += v0[j] * w;
      acc1 += v1[j] * w;
    }
  }
  f32x4 q = acc0 * acc0 + acc1 * acc1;
  float s2 = q.x + q.y + q.z + q.w;
  s2 = xred_sum(s2);
  if (lane == 0) s2s[wv] = s2;
  __syncthreads();
  float sn = sqrtf(s2s[0] + s2s[1] + s2s[2] + s2s[3]);
  float inv = 1.0f / fmaxf(sn, 1e-12f);
  __hip_bfloat16* dst = cb + ((long)m * P_CLS + p) * D_DIM;
  f32x4 o0 = acc0 * inv, o1 = acc1 * inv;
  ushort4 h0, h1;
  h0.x = f2bf_bits(o0.x); h0.y = f2bf_bits(o0.y);
  h0.z = f2bf_bits(o0.z); h0.w = f2bf_bits(o0.w);
  h1.x = f2bf_bits(o1.x); h1.y = f2bf_bits(o1.y);
  h1.z = f2bf_bits(o1.z); h1.w = f2bf_bits(o1.w);
  *(ushort4*)(dst + col0) = h0;
  *(ushort4*)(dst + col0 + 256) = h1;
  if (t == 0 && c > 0) atomicAdd(&accs[0], sn);
}

// Split-K bf16 MFMA GEMM (gridDim.z slices), 64x64 tiles, LDS double-buffer
// + depth-2 reg prefetch, one barrier per K-step.
__global__ __launch_bounds__(256)
void k_gemm(const __hip_bfloat16* __restrict__ cbh, float* __restrict__ logits) {
  __shared__ __align__(16) unsigned short As[2][64 * 40], Bs[2][64 * 40];
  int pair = blockIdx.y, kz = blockIdx.z, nkz = gridDim.z;
  int ksl = D_DIM / nkz;
  int ma = (pair == 2) ? 1 : 0;
  int mb = (pair == 0) ? 1 : 2;
  const unsigned short* A =
      (const unsigned short*)cbh + (long)ma * P_CLS * D_DIM + kz * ksl;
  const unsigned short* B =
      (const unsigned short*)cbh + (long)mb * P_CLS * D_DIM + kz * ksl;
  float* C = logits + ((long)kz * 3 + pair) * P_CLS * P_CLS;
  int tm = (blockIdx.x >> 3) * 64, tn = (blockIdx.x & 7) * 64;
  int t = threadIdx.x, lane = t & 63, wv = t >> 6;
  int srow = t >> 2, skc = (t & 3) * 8;
  int quad = lane >> 4, mr = lane & 15;
  const unsigned short* pa = A + (long)(tm + srow) * D_DIM + skc;
  const unsigned short* pb = B + (long)(tn + srow) * D_DIM + skc;
  f32x4 acc[4] = {{0,0,0,0},{0,0,0,0},{0,0,0,0},{0,0,0,0}};
  uint4 av = *(const uint4*)pa, bv = *(const uint4*)pb;
  *(uint4*)(&As[0][srow * 40 + skc]) = av;
  *(uint4*)(&Bs[0][srow * 40 + skc]) = bv;
  av = *(const uint4*)(pa + 32); bv = *(const uint4*)(pb + 32);
  const int NIT = ksl / 32;
  for (int it = 0; it < NIT; ++it) {
    __syncthreads();
    int cur = it & 1;
    if (it + 1 < NIT) {
      *(uint4*)(&As[cur ^ 1][srow * 40 + skc]) = av;
      *(uint4*)(&Bs[cur ^ 1][srow * 40 + skc]) = bv;
    }
    if (it + 2 < NIT) {
      av = *(const uint4*)(pa + (it + 2) * 32);
      bv = *(const uint4*)(pb + (it + 2) * 32);
    }
    short8 af = *(const short8*)(&As[cur][(wv * 16 + mr) * 40 + quad * 8]);
#pragma unroll
    for (int nb = 0; nb < 4; ++nb) {
      short8 bfr = *(const short8*)(&Bs[cur][(nb * 16 + mr) * 40 + quad * 8]);
      acc[nb] = __builtin_amdgcn_mfma_f32_16x16x32_bf16(af, bfr, acc[nb], 0, 0, 0);
    }
  }
  int crow = tm + wv * 16 + quad * 4;
#pragma unroll
  for (int nb = 0; nb < 4; ++nb)
#pragma unroll
    for (int r = 0; r < 4; ++r)
      C[(long)(crow + r) * P_CLS + tn + nb * 16 + mr] = acc[nb][r] * TAU_INV;
}

// One block per (pair,p) row: sum nkz split-K partials, logsumexp - diag.
__global__ __launch_bounds__(256)
void k_lse(const float* __restrict__ logits, float* __restrict__ accs, int nkz) {
  __shared__ float sred[8];
  int row = blockIdx.x;  // 0 .. 3*P-1
  int p = row & (P_CLS - 1);
  int t = threadIdx.x, lane = t & 63, wv = t >> 6;
  float v0 = 0.f, v1 = 0.f;
  for (int z = 0; z < nkz; ++z) {
    const float* L = logits + ((long)z * 3 * P_CLS + row) * P_CLS;
    v0 += L[t];
    v1 += L[t + 256];
  }
  float mx = xred_max(fmaxf(v0, v1));
  if (lane == 0) sred[wv] = mx;
  __syncthreads();
  mx = fmaxf(fmaxf(sred[0], sred[1]), fmaxf(sred[2], sred[3]));
  float e = expf(v0 - mx) + expf(v1 - mx);
  e = xred_sum(e);
  if (lane == 0) sred[4 + wv] = e;
  __syncthreads();
  if (t == 0) {
    float tot = sred[4] + sred[5] + sred[6] + sred[7];
    float diag = 0.f;
    for (int z = 0; z < nkz; ++z)
      diag += logits[((long)z * 3 * P_CLS + row) * P_CLS + p];
    atomicAdd(&accs[1], mx + logf(tot) - diag);
  }
}

__global__ void k_final(const float* __restrict__ accs, float* __restrict__ out,
                        float invN) {
  out[0] = 6.0f - 2.0f * invN * accs[0] + accs[1] * (1.0f / (float)P_CLS);
}

extern "C" void kernel_launch(void* const* d_in, const int* in_sizes, int n_in,
                              void* d_out, int out_size, void* d_ws, size_t ws_size,
                              hipStream_t stream) {
  const float* fvp = (const float*)d_in[0];
  const float* fap = (const float*)d_in[1];
  const float* frp = (const float*)d_in[2];
  const int* label = (const int*)d_in[3];
  int N = in_sizes[3];

  char* ws = (char*)d_ws;
  int* cnt = (int*)ws;                                    // 2 KiB
  int* idx = (int*)(ws + 2048);                           // 64 KiB
  float* accs = (float*)(ws + 2048 + 65536);              // 32 B
  __hip_bfloat16* cb = (__hip_bfloat16*)(ws + 131072);    // 6 MiB
  float* logits = (float*)(ws + 131072 + 3ul * P_CLS * D_DIM * 2);

  size_t base = 131072 + 3ul * P_CLS * D_DIM * 2;
  size_t per_z = 3ul * P_CLS * P_CLS * 4;
  int KZ = (ws_size >= base + 4 * per_z) ? 4 : 2;

  hipLaunchKernelGGL(k_prep, dim3(1), dim3(1024), 0, stream, label, cnt, idx,
                     accs, N);
  hipLaunchKernelGGL(k_centers, dim3(P_CLS, 3), dim3(256), 0, stream,
                     fvp, fap, frp, cnt, idx, cb, accs);
  hipLaunchKernelGGL(k_gemm, dim3(64, 3, KZ), dim3(256), 0, stream, cb, logits);
  hipLaunchKernelGGL(k_lse, dim3(3 * P_CLS), dim3(256), 0, stream, logits, accs, KZ);
  hipLaunchKernelGGL(k_final, dim3(1), dim3(1), 0, stream, accs, (float*)d_out,
                     1.0f / (float)N);
}

// Round 7
// 240.144 us; speedup vs baseline: 1.1214x; 1.0402x over previous
//
#include <hip/hip_runtime.h>
#include <hip/hip_bf16.h>

#define P_CLS 512
#define D_DIM 2048
#define CAP   32
#define TAU_INV 2.0f

typedef short short8 __attribute__((ext_vector_type(8)));
typedef float f32x4 __attribute__((ext_vector_type(4)));

__device__ __forceinline__ unsigned short f2bf_bits(float x) {
  __hip_bfloat16 b = __float2bfloat16(x);
  unsigned short u;
  __builtin_memcpy(&u, &b, sizeof(u));
  return u;
}

__device__ __forceinline__ float xred_sum(float v) {
#pragma unroll
  for (int o = 1; o < 64; o <<= 1) v += __shfl_xor(v, o, 64);
  return v;
}
__device__ __forceinline__ float xred_max(float v) {
#pragma unroll
  for (int o = 1; o < 64; o <<= 1) v = fmaxf(v, __shfl_xor(v, o, 64));
  return v;
}

// Block per (class p, modality m). Self-indexes its class from label[].
// Wave wv owns cols [wv*512, wv*512+512). Rows in groups of 8: 16
// global_load_dwordx4 issued from ONE asm block (SGPR base + voffset,
// +1024B imm for the second half) ending in s_waitcnt vmcnt(0) --
// the RA cannot sink these; 16 KB/wave guaranteed in flight.
__global__ __launch_bounds__(256, 4)
void k_centers(const float* __restrict__ f0, const float* __restrict__ f1,
               const float* __restrict__ f2, const int* __restrict__ label,
               int n, __hip_bfloat16* __restrict__ cb,
               float* __restrict__ snorm) {
  __shared__ int lidx[CAP];
  __shared__ int lcnt;
  __shared__ f32x4 scr[2][4][2];
  __shared__ float s2s[4];
  int p = blockIdx.x, m = blockIdx.y;
  const float* F = (m == 0) ? f0 : (m == 1) ? f1 : f2;
  int t = threadIdx.x, lane = t & 63, wv = t >> 6;
  if (t == 0) lcnt = 0;
  __syncthreads();
  for (int j = t; j < n; j += 256) {
    if (label[j] == p) {
      int s_ = atomicAdd(&lcnt, 1);
      if (s_ < CAP) lidx[s_] = j;
    }
  }
  __syncthreads();
  int c = lcnt;
  if (c > CAP) c = CAP;

  unsigned voff = (unsigned)((wv * 512 + lane * 4) * 4);  // byte offset in row
  f32x4 acc0 = {0, 0, 0, 0}, acc1 = {0, 0, 0, 0};
  int ng = (c + 7) >> 3;
  for (int g = 0; g < ng; ++g) {
    int rbase = g * 8;
    const float* b0;
    const float* b1;
    const float* b2;
    const float* b3;
    const float* b4;
    const float* b5;
    const float* b6;
    const float* b7;
#define ROWPTR(J, B)                                        \
    {                                                       \
      int rr = rbase + J;                                   \
      if (rr >= c) rr = c - 1;                              \
      int ri = __builtin_amdgcn_readfirstlane(lidx[rr]);    \
      B = F + (long)ri * D_DIM;                             \
    }
    ROWPTR(0, b0) ROWPTR(1, b1) ROWPTR(2, b2) ROWPTR(3, b3)
    ROWPTR(4, b4) ROWPTR(5, b5) ROWPTR(6, b6) ROWPTR(7, b7)
#undef ROWPTR
    f32x4 v0[8], v1[8];
    asm volatile(
        "global_load_dwordx4 %0, %24, %16\n\t"
        "global_load_dwordx4 %8, %24, %16 offset:1024\n\t"
        "global_load_dwordx4 %1, %24, %17\n\t"
        "global_load_dwordx4 %9, %24, %17 offset:1024\n\t"
        "global_load_dwordx4 %2, %24, %18\n\t"
        "global_load_dwordx4 %10, %24, %18 offset:1024\n\t"
        "global_load_dwordx4 %3, %24, %19\n\t"
        "global_load_dwordx4 %11, %24, %19 offset:1024\n\t"
        "global_load_dwordx4 %4, %24, %20\n\t"
        "global_load_dwordx4 %12, %24, %20 offset:1024\n\t"
        "global_load_dwordx4 %5, %24, %21\n\t"
        "global_load_dwordx4 %13, %24, %21 offset:1024\n\t"
        "global_load_dwordx4 %6, %24, %22\n\t"
        "global_load_dwordx4 %14, %24, %22 offset:1024\n\t"
        "global_load_dwordx4 %7, %24, %23\n\t"
        "global_load_dwordx4 %15, %24, %23 offset:1024\n\t"
        "s_waitcnt vmcnt(0)"
        : "=v"(v0[0]), "=v"(v0[1]), "=v"(v0[2]), "=v"(v0[3]),
          "=v"(v0[4]), "=v"(v0[5]), "=v"(v0[6]), "=v"(v0[7]),
          "=v"(v1[0]), "=v"(v1[1]), "=v"(v1[2]), "=v"(v1[3]),
          "=v"(v1[4]), "=v"(v1[5]), "=v"(v1[6]), "=v"(v1[7])
        : "s"(b0), "s"(b1), "s"(b2), "s"(b3),
          "s"(b4), "s"(b5), "s"(b6), "s"(b7), "v"(voff)
        : "memory");
    f32x4 sa, sb;
#pragma unroll
    for (int j = 0; j < 4; ++j) {
      f32x4 qa = v0[j] * v0[j] + v1[j] * v1[j];
      sa[j] = qa.x + qa.y + qa.z + qa.w;
      f32x4 qb = v0[j + 4] * v0[j + 4] + v1[j + 4] * v1[j + 4];
      sb[j] = qb.x + qb.y + qb.z + qb.w;
    }
#pragma unroll
    for (int o = 1; o < 64; o <<= 1) {
#pragma unroll
      for (int j = 0; j < 4; ++j) {
        sa[j] += __shfl_xor(sa[j], o, 64);
        sb[j] += __shfl_xor(sb[j], o, 64);
      }
    }
    int par = g & 1;
    if (lane == 0) {
      scr[par][wv][0] = sa;
      scr[par][wv][1] = sb;
    }
    __syncthreads();
    f32x4 ta = scr[par][0][0] + scr[par][1][0] + scr[par][2][0] + scr[par][3][0];
    f32x4 tb = scr[par][0][1] + scr[par][1][1] + scr[par][2][1] + scr[par][3][1];
#pragma unroll
    for (int j = 0; j < 8; ++j) {
      float tot = (j < 4) ? ta[j] : tb[j - 4];
      float w = (rbase + j < c) ? (1.0f / fmaxf(sqrtf(tot), 1e-12f)) : 0.f;
      acc0 += v0[j] * w;
      acc1 += v1[j] * w;
    }
  }
  f32x4 q = acc0 * acc0 + acc1 * acc1;
  float s2 = q.x + q.y + q.z + q.w;
  s2 = xred_sum(s2);
  if (lane == 0) s2s[wv] = s2;
  __syncthreads();
  float sn = sqrtf(s2s[0] + s2s[1] + s2s[2] + s2s[3]);
  float inv = 1.0f / fmaxf(sn, 1e-12f);
  int col0 = wv * 512 + lane * 4;
  __hip_bfloat16* dst = cb + ((long)m * P_CLS + p) * D_DIM;
  f32x4 o0 = acc0 * inv, o1 = acc1 * inv;
  ushort4 h0, h1;
  h0.x = f2bf_bits(o0.x); h0.y = f2bf_bits(o0.y);
  h0.z = f2bf_bits(o0.z); h0.w = f2bf_bits(o0.w);
  h1.x = f2bf_bits(o1.x); h1.y = f2bf_bits(o1.y);
  h1.z = f2bf_bits(o1.z); h1.w = f2bf_bits(o1.w);
  *(ushort4*)(dst + col0) = h0;
  *(ushort4*)(dst + col0 + 256) = h1;
  if (t == 0) snorm[m * P_CLS + p] = (c > 0) ? sn : 0.f;
}

// Split-K bf16 MFMA GEMM (gridDim.z slices), 64x64 tiles, LDS double-buffer
// + depth-2 reg prefetch, one barrier per K-step.
__global__ __launch_bounds__(256)
void k_gemm(const __hip_bfloat16* __restrict__ cbh, float* __restrict__ logits) {
  __shared__ __align__(16) unsigned short As[2][64 * 40], Bs[2][64 * 40];
  int pair = blockIdx.y, kz = blockIdx.z, nkz = gridDim.z;
  int ksl = D_DIM / nkz;
  int ma = (pair == 2) ? 1 : 0;
  int mb = (pair == 0) ? 1 : 2;
  const unsigned short* A =
      (const unsigned short*)cbh + (long)ma * P_CLS * D_DIM + kz * ksl;
  const unsigned short* B =
      (const unsigned short*)cbh + (long)mb * P_CLS * D_DIM + kz * ksl;
  float* C = logits + ((long)kz * 3 + pair) * P_CLS * P_CLS;
  int tm = (blockIdx.x >> 3) * 64, tn = (blockIdx.x & 7) * 64;
  int t = threadIdx.x, lane = t & 63, wv = t >> 6;
  int srow = t >> 2, skc = (t & 3) * 8;
  int quad = lane >> 4, mr = lane & 15;
  const unsigned short* pa = A + (long)(tm + srow) * D_DIM + skc;
  const unsigned short* pb = B + (long)(tn + srow) * D_DIM + skc;
  f32x4 acc[4] = {{0,0,0,0},{0,0,0,0},{0,0,0,0},{0,0,0,0}};
  uint4 av = *(const uint4*)pa, bv = *(const uint4*)pb;
  *(uint4*)(&As[0][srow * 40 + skc]) = av;
  *(uint4*)(&Bs[0][srow * 40 + skc]) = bv;
  av = *(const uint4*)(pa + 32); bv = *(const uint4*)(pb + 32);
  const int NIT = ksl / 32;
  for (int it = 0; it < NIT; ++it) {
    __syncthreads();
    int cur = it & 1;
    if (it + 1 < NIT) {
      *(uint4*)(&As[cur ^ 1][srow * 40 + skc]) = av;
      *(uint4*)(&Bs[cur ^ 1][srow * 40 + skc]) = bv;
    }
    if (it + 2 < NIT) {
      av = *(const uint4*)(pa + (it + 2) * 32);
      bv = *(const uint4*)(pb + (it + 2) * 32);
    }
    short8 af = *(const short8*)(&As[cur][(wv * 16 + mr) * 40 + quad * 8]);
#pragma unroll
    for (int nb = 0; nb < 4; ++nb) {
      short8 bfr = *(const short8*)(&Bs[cur][(nb * 16 + mr) * 40 + quad * 8]);
      acc[nb] = __builtin_amdgcn_mfma_f32_16x16x32_bf16(af, bfr, acc[nb], 0, 0, 0);
    }
  }
  int crow = tm + wv * 16 + quad * 4;
#pragma unroll
  for (int nb = 0; nb < 4; ++nb)
#pragma unroll
    for (int r = 0; r < 4; ++r)
      C[(long)(crow + r) * P_CLS + tn + nb * 16 + mr] = acc[nb][r] * TAU_INV;
}

// One block per (pair,p) row: sum nkz split-K partials, rowloss = lse - diag.
__global__ __launch_bounds__(256)
void k_lse(const float* __restrict__ logits, float* __restrict__ rowloss,
           int nkz) {
  __shared__ float sred[8];
  int row = blockIdx.x;  // 0 .. 3*P-1
  int p = row & (P_CLS - 1);
  int t = threadIdx.x, lane = t & 63, wv = t >> 6;
  float v0 = 0.f, v1 = 0.f;
  for (int z = 0; z < nkz; ++z) {
    const float* L = logits + ((long)z * 3 * P_CLS + row) * P_CLS;
    v0 += L[t];
    v1 += L[t + 256];
  }
  float mx = xred_max(fmaxf(v0, v1));
  if (lane == 0) sred[wv] = mx;
  __syncthreads();
  mx = fmaxf(fmaxf(sred[0], sred[1]), fmaxf(sred[2], sred[3]));
  float e = expf(v0 - mx) + expf(v1 - mx);
  e = xred_sum(e);
  if (lane == 0) sred[4 + wv] = e;
  __syncthreads();
  if (t == 0) {
    float tot = sred[4] + sred[5] + sred[6] + sred[7];
    float diag = 0.f;
    for (int z = 0; z < nkz; ++z)
      diag += logits[((long)z * 3 * P_CLS + row) * P_CLS + p];
    rowloss[row] = mx + logf(tot) - diag;
  }
}

// Reduce snorm[1536] and rowloss[1536], compose scalar.
__global__ __launch_bounds__(256)
void k_final(const float* __restrict__ snorm, const float* __restrict__ rowloss,
             float* __restrict__ out, float invN) {
  __shared__ float sh[8];
  int t = threadIdx.x, lane = t & 63, wv = t >> 6;
  float s = 0.f, l = 0.f;
  for (int j = t; j < 3 * P_CLS; j += 256) {
    s += snorm[j];
    l += rowloss[j];
  }
  s = xred_sum(s);
  l = xred_sum(l);
  if (lane == 0) { sh[wv] = s; sh[4 + wv] = l; }
  __syncthreads();
  if (t == 0) {
    float st = sh[0] + sh[1] + sh[2] + sh[3];
    float lt = sh[4] + sh[5] + sh[6] + sh[7];
    out[0] = 6.0f - 2.0f * invN * st + lt * (1.0f / (float)P_CLS);
  }
}

extern "C" void kernel_launch(void* const* d_in, const int* in_sizes, int n_in,
                              void* d_out, int out_size, void* d_ws, size_t ws_size,
                              hipStream_t stream) {
  const float* fvp = (const float*)d_in[0];
  const float* fap = (const float*)d_in[1];
  const float* frp = (const float*)d_in[2];
  const int* label = (const int*)d_in[3];
  int N = in_sizes[3];

  char* ws = (char*)d_ws;
  float* snorm = (float*)ws;                       // 6 KiB
  float* rowloss = (float*)(ws + 8192);            // 6 KiB
  __hip_bfloat16* cb = (__hip_bfloat16*)(ws + 16384);  // 6 MiB
  float* logits = (float*)(ws + 16384 + 3ul * P_CLS * D_DIM * 2);

  size_t base = 16384 + 3ul * P_CLS * D_DIM * 2;
  size_t per_z = 3ul * P_CLS * P_CLS * 4;
  int KZ = (ws_size >= base + 4 * per_z) ? 4 : 2;

  hipLaunchKernelGGL(k_centers, dim3(P_CLS, 3), dim3(256), 0, stream,
                     fvp, fap, frp, label, N, cb, snorm);
  hipLaunchKernelGGL(k_gemm, dim3(64, 3, KZ), dim3(256), 0, stream, cb, logits);
  hipLaunchKernelGGL(k_lse, dim3(3 * P_CLS), dim3(256), 0, stream, logits,
                     rowloss, KZ);
  hipLaunchKernelGGL(k_final, dim3(1), dim3(256), 0, stream, snorm, rowloss,
                     (float*)d_out, 1.0f / (float)N);
}